// Round 12
// baseline (266.018 us; speedup 1.0000x reference)
//
#include <hip/hip_runtime.h>
#include <hip/hip_fp16.h>

#define D 128
#define SCAN_B 256

typedef __attribute__((ext_vector_type(8))) _Float16 f16x8;
typedef __attribute__((ext_vector_type(4))) float f32x4;

typedef __attribute__((address_space(1))) const void gas_t;
typedef __attribute__((address_space(3))) void las_t;

// ---- hierarchical exclusive scan (2 kernels: pass1 + fused pass3) ----
__global__ void scan_pass1(const int* __restrict__ cnt, int* __restrict__ rs,
                           int* __restrict__ bsum, int N) {
    __shared__ int lds[SCAN_B];
    int tid = threadIdx.x;
    int i = blockIdx.x * SCAN_B + tid;
    int v = (i < N) ? cnt[i] : 0;
    lds[tid] = v;
    __syncthreads();
    for (int o = 1; o < SCAN_B; o <<= 1) {
        int t = (tid >= o) ? lds[tid - o] : 0;
        __syncthreads();
        lds[tid] += t;
        __syncthreads();
    }
    if (i < N) rs[i] = lds[tid] - v;
    if (tid == SCAN_B - 1) bsum[blockIdx.x] = lds[tid];
}

// fused: each block redundantly scans bsum (nb <= 256) to get its own offset
__global__ void scan_pass3(int* __restrict__ rs, int* __restrict__ cursor,
                           const int* __restrict__ bsum, const int* __restrict__ cnt,
                           float* __restrict__ inv, int N, int nb) {
    __shared__ int lds[SCAN_B];
    int tid = threadIdx.x;
    int v = (tid < nb) ? bsum[tid] : 0;
    lds[tid] = v;
    __syncthreads();
    for (int o = 1; o < SCAN_B; o <<= 1) {
        int t = (tid >= o) ? lds[tid - o] : 0;
        __syncthreads();
        lds[tid] += t;
        __syncthreads();
    }
    int boff = (blockIdx.x == 0) ? 0 : lds[blockIdx.x - 1];
    int i = blockIdx.x * SCAN_B + tid;
    if (i < N) {
        int vv = rs[i] + boff;
        rs[i] = vv;
        cursor[i] = vv;
        inv[i] = 1.0f / (float)max(cnt[i], 1);
    }
}

__global__ void fill_kernel(const int* __restrict__ ei, int E,
                            int* __restrict__ cursor, int* __restrict__ csr) {
    int e = blockIdx.x * blockDim.x + threadIdx.x;
    if (e < E) {
        int src = ei[e], dst = ei[E + e];
        int pos = atomicAdd(&cursor[dst], 1);
        csr[pos] = src;
    }
}

// ---- fused prologue: weight pack | fp32->f16 hi/lo cvt | degree count ----
__global__ void prologue_kernel(const float* __restrict__ W1l, const float* __restrict__ W1r,
                                const float* __restrict__ W2l, const float* __restrict__ W2r,
                                const float* __restrict__ Wf, unsigned short* __restrict__ pw,
                                const float* __restrict__ x, __half* __restrict__ xh,
                                __half* __restrict__ xl, int n8,
                                const int* __restrict__ ei, int E, int* __restrict__ cnt) {
    int t = blockIdx.x * blockDim.x + threadIdx.x;
    if (t < 10240) {
        int idx = t;
        int w = idx >> 11;
        int r = idx & 2047;
        int ks = r >> 9;
        int tt = (r >> 6) & 7;
        int lane = r & 63;
        int q = lane >> 4, n = lane & 15;
        const float* W = (w == 0) ? W1l : (w == 1) ? W1r : (w == 2) ? W2l : (w == 3) ? W2r : Wf;
        unsigned short* dh = pw + (size_t)w * 32768;
        unsigned short* dl = dh + 16384;
        int off = ((ks * 8 + tt) * 64 + lane) * 8;
#pragma unroll
        for (int j = 0; j < 8; j++) {
            float v = W[(size_t)(ks * 32 + q * 8 + j) * D + tt * 16 + n];
            __half hb = __float2half_rn(v);
            dh[off + j] = __half_as_ushort(hb);
            dl[off + j] = __half_as_ushort(__float2half_rn(v - __half2float(hb)));
        }
    } else if (t < 10240 + n8) {
        int i = t - 10240;
        const float4* x4 = (const float4*)x;
        float4 a = x4[2 * i], b = x4[2 * i + 1];
        float v[8] = {a.x, a.y, a.z, a.w, b.x, b.y, b.z, b.w};
        uint4 oh, ol;
        __half2* ph = (__half2*)&oh;
        __half2* pl = (__half2*)&ol;
#pragma unroll
        for (int jj = 0; jj < 4; jj++) {
            __half h0 = __float2half_rn(v[2 * jj]);
            __half h1 = __float2half_rn(v[2 * jj + 1]);
            ph[jj] = __halves2half2(h0, h1);
            pl[jj] = __halves2half2(__float2half_rn(v[2 * jj] - __half2float(h0)),
                                    __float2half_rn(v[2 * jj + 1] - __half2float(h1)));
        }
        ((uint4*)xh)[i] = oh;
        ((uint4*)xl)[i] = ol;
    } else {
        int e = t - 10240 - n8;
        if (e < E) atomicAdd(&cnt[ei[E + e]], 1);
    }
}

__device__ __forceinline__ void acc8(uint4 v, float* s) {
    const __half2* h = reinterpret_cast<const __half2*>(&v);
    float2 f0 = __half22float2(h[0]);
    float2 f1 = __half22float2(h[1]);
    float2 f2 = __half22float2(h[2]);
    float2 f3 = __half22float2(h[3]);
    s[0] += f0.x; s[1] += f0.y; s[2] += f1.x; s[3] += f1.y;
    s[4] += f2.x; s[5] += f2.y; s[6] += f3.x; s[7] += f3.y;
}

// ---- gather-mean aggregate: 16 lanes/node, 8 cols/lane (round-6 proven shape) ----
__global__ void aggregate_kernel(const __half* __restrict__ xh, int sstride,
                                 const int* __restrict__ csr,
                                 const int* __restrict__ rs, const int* __restrict__ cnt,
                                 const float* __restrict__ inv,
                                 __half* __restrict__ aggh, __half* __restrict__ aggl, int N) {
    int t = blockIdx.x * blockDim.x + threadIdx.x;
    int node = t >> 4;
    int c = t & 15;
    if (node >= N) return;
    int deg = cnt[node];
    int st = rs[node];
    const uint4* x4 = (const uint4*)xh;
    float s[8] = {0.f, 0.f, 0.f, 0.f, 0.f, 0.f, 0.f, 0.f};
    int i = 0;
    for (; i + 4 <= deg; i += 4) {
        int n0 = csr[st + i + 0], n1 = csr[st + i + 1];
        int n2 = csr[st + i + 2], n3 = csr[st + i + 3];
        uint4 v0 = x4[(size_t)n0 * sstride + c];
        uint4 v1 = x4[(size_t)n1 * sstride + c];
        uint4 v2 = x4[(size_t)n2 * sstride + c];
        uint4 v3 = x4[(size_t)n3 * sstride + c];
        acc8(v0, s); acc8(v1, s); acc8(v2, s); acc8(v3, s);
    }
    for (; i < deg; i++) {
        int n0 = csr[st + i];
        uint4 v0 = x4[(size_t)n0 * sstride + c];
        acc8(v0, s);
    }
    float iv = inv[node];
    uint4 oh, ol;
    __half2* ph = (__half2*)&oh;
    __half2* pl = (__half2*)&ol;
#pragma unroll
    for (int jj = 0; jj < 4; jj++) {
        float v0 = s[2 * jj] * iv, v1 = s[2 * jj + 1] * iv;
        __half h0 = __float2half_rn(v0), h1 = __float2half_rn(v1);
        ph[jj] = __halves2half2(h0, h1);
        pl[jj] = __halves2half2(__float2half_rn(v0 - __half2float(h0)),
                                __float2half_rn(v1 - __half2float(h1)));
    }
    ((uint4*)aggh)[(size_t)node * 16 + c] = oh;
    ((uint4*)aggl)[(size_t)node * 16 + c] = ol;
}

// ---- full-row-wave MFMA GEMM, round-6 32KB W double-buffer, A fully hoisted ----
// block = 4 waves x 16 rows. grid = ceil(N/64). K=256 in 8 steps.
// ALL 16 A-loads issued in one burst at kernel entry (256B/lane in flight, decoupled
// from the W-drain barriers). W staged 2-ahead via global_load_lds (round-6 proven).
template <int LAYER>
__global__ __launch_bounds__(256, 1) void mfma_gemm(
        const uint4* __restrict__ Agh, const uint4* __restrict__ Agl,  // stride 16 uint4/row
        const uint4* __restrict__ Ah1, const uint4* __restrict__ Al1,  // x (s16) or h1 (s32)
        const uint4* __restrict__ W0h, const uint4* __restrict__ W0l,
        const uint4* __restrict__ W1h, const uint4* __restrict__ W1l,
        const float* __restrict__ bias,
        const uint4* __restrict__ W2h, const uint4* __restrict__ W2l,
        const float* __restrict__ bias2,
        float* out, __half* Hout, int N) {
    __shared__ uint4 smem4[2048];   // 32 KB: W double-buffer; LAYER2 reuses for H staging

    const int tid = threadIdx.x;
    const int lane = tid & 63;
    const int wave = tid >> 6;
    const int c = lane & 15;
    const int q = lane >> 4;
    const int R = blockIdx.x * 64 + wave * 16;
    const int row0 = min(R + c, N - 1);
    const size_t rb16 = (size_t)row0 * 16 + q;
    const size_t rbA1 = (size_t)row0 * (LAYER == 1 ? 16 : 32) + q;

#define STAGE_W(ks_, b_)                                                                   \
    do {                                                                                   \
        const uint4* sh_ = (((ks_) < 4) ? W0h : W1h) + (size_t)((ks_) & 3) * 512;          \
        const uint4* sl_ = (((ks_) < 4) ? W0l : W1l) + (size_t)((ks_) & 3) * 512;          \
        const uint4* s_ = ((wave < 2) ? sh_ : sl_) + ((wave & 1) * 256 + lane);            \
        uint4* d_ = smem4 + (b_) * 1024 + (wave >> 1) * 512 + (wave & 1) * 256;            \
        __builtin_amdgcn_global_load_lds((gas_t*)(s_), (las_t*)(d_), 16, 0, 0);            \
        __builtin_amdgcn_global_load_lds((gas_t*)(s_ + 64), (las_t*)(d_ + 64), 16, 0, 0);  \
        __builtin_amdgcn_global_load_lds((gas_t*)(s_ + 128), (las_t*)(d_ + 128), 16, 0, 0);\
        __builtin_amdgcn_global_load_lds((gas_t*)(s_ + 192), (las_t*)(d_ + 192), 16, 0, 0);\
    } while (0)

    // ---- one burst: all 16 A fragments + first two W stages ----
    uint4 A_h[8], A_l[8];
#pragma unroll
    for (int kl = 0; kl < 4; kl++) {
        A_h[kl] = Agh[rb16 + kl * 4];
        A_l[kl] = Agl[rb16 + kl * 4];
        A_h[4 + kl] = Ah1[rbA1 + kl * 4];
        A_l[4 + kl] = Al1[rbA1 + kl * 4];
    }
    STAGE_W(0, 0);
    STAGE_W(1, 1);
    asm volatile("s_waitcnt vmcnt(0)" ::: "memory");
    __syncthreads();

    f32x4 acc[8];
#pragma unroll
    for (int t = 0; t < 8; t++)
#pragma unroll
        for (int r = 0; r < 4; r++) acc[t][r] = 0.0f;

#pragma unroll
    for (int ks = 0; ks < 8; ks++) {
        const int b = ks & 1;
        const uint4* wb = smem4 + b * 1024;
        f16x8 ah = __builtin_bit_cast(f16x8, A_h[ks]);
        f16x8 al = __builtin_bit_cast(f16x8, A_l[ks]);
#pragma unroll
        for (int t = 0; t < 8; t++) {
            f16x8 bh = __builtin_bit_cast(f16x8, wb[t * 64 + lane]);
            f16x8 bl = __builtin_bit_cast(f16x8, wb[512 + t * 64 + lane]);
            acc[t] = __builtin_amdgcn_mfma_f32_16x16x32_f16(ah, bh, acc[t], 0, 0, 0);
            acc[t] = __builtin_amdgcn_mfma_f32_16x16x32_f16(al, bh, acc[t], 0, 0, 0);
            acc[t] = __builtin_amdgcn_mfma_f32_16x16x32_f16(ah, bl, acc[t], 0, 0, 0);
        }
        if (ks < 7) {
            asm volatile("s_waitcnt vmcnt(0)" ::: "memory");  // stage(ks+1) landed
            __syncthreads();
            if (ks < 6) STAGE_W(ks + 2, b);   // overwrite just-consumed buffer
        }
    }

    // bias + row L2-norm (whole row in this wave: 16-lane shfl reduce) + relu
#pragma unroll
    for (int t = 0; t < 8; t++) {
        float bv = bias[t * 16 + c];
#pragma unroll
        for (int r = 0; r < 4; r++) acc[t][r] += bv;
    }
#pragma unroll
    for (int r = 0; r < 4; r++) {
        float v = 0.0f;
#pragma unroll
        for (int t = 0; t < 8; t++) v += acc[t][r] * acc[t][r];
        v += __shfl_xor(v, 1, 16);
        v += __shfl_xor(v, 2, 16);
        v += __shfl_xor(v, 4, 16);
        v += __shfl_xor(v, 8, 16);
        float rn = 1.0f / fmaxf(sqrtf(v), 1e-12f);
#pragma unroll
        for (int t = 0; t < 8; t++) acc[t][r] = fmaxf(acc[t][r] * rn, 0.0f);
    }

    if (LAYER == 1) {
        // write h1 row-interleaved: per row, halfs [0..127]=hi, [128..255]=lo
#pragma unroll
        for (int t = 0; t < 8; t++)
#pragma unroll
            for (int r = 0; r < 4; r++) {
                int row = R + q * 4 + r;
                if (row < N) {
                    float v = acc[t][r];
                    __half h = __float2half_rn(v);
                    size_t base = (size_t)row * 256;
                    Hout[base + t * 16 + c] = h;
                    Hout[base + 128 + t * 16 + c] = __float2half_rn(v - __half2float(h));
                }
            }
        return;
    }

    // ---- fused FC (round-6 form: H in LDS, W2 direct from global) ----
    __syncthreads();  // all waves done reading the weight double-buffer
    unsigned short* hw = (unsigned short*)(smem4 + wave * 512);
#pragma unroll
    for (int t = 0; t < 8; t++)
#pragma unroll
        for (int r = 0; r < 4; r++) {
            int m = q * 4 + r;
            float v = acc[t][r];
            __half h = __float2half_rn(v);
            int j4 = (t * 2 + (c >> 3)) ^ (m & 7);
            int off = m * 128 + j4 * 8 + (c & 7);
            hw[off] = __half_as_ushort(h);
            hw[2048 + off] = __half_as_ushort(__float2half_rn(v - __half2float(h)));
        }
    // wave-private RAW: compiler orders via lgkmcnt; no barrier needed
    uint4 a2h_[4], a2l_[4];
#pragma unroll
    for (int k2 = 0; k2 < 4; k2++) {
        int r4 = (k2 * 4 + q) ^ (c & 7);
        a2h_[k2] = *(const uint4*)(hw + c * 128 + r4 * 8);
        a2l_[k2] = *(const uint4*)(hw + 2048 + c * 128 + r4 * 8);
    }

    f32x4 acc2[8];
#pragma unroll
    for (int t = 0; t < 8; t++) {
        float bv = bias2[t * 16 + c];
#pragma unroll
        for (int r = 0; r < 4; r++) acc2[t][r] = bv;
    }
#pragma unroll
    for (int k2 = 0; k2 < 4; k2++) {
        const uint4* Wh = W2h + (size_t)k2 * 512 + lane;
        const uint4* Wl = W2l + (size_t)k2 * 512 + lane;
        f16x8 ah = __builtin_bit_cast(f16x8, a2h_[k2]);
        f16x8 al = __builtin_bit_cast(f16x8, a2l_[k2]);
#pragma unroll
        for (int t = 0; t < 8; t++) {
            f16x8 bh = __builtin_bit_cast(f16x8, Wh[t * 64]);
            f16x8 bl = __builtin_bit_cast(f16x8, Wl[t * 64]);
            acc2[t] = __builtin_amdgcn_mfma_f32_16x16x32_f16(ah, bh, acc2[t], 0, 0, 0);
            acc2[t] = __builtin_amdgcn_mfma_f32_16x16x32_f16(al, bh, acc2[t], 0, 0, 0);
            acc2[t] = __builtin_amdgcn_mfma_f32_16x16x32_f16(ah, bl, acc2[t], 0, 0, 0);
        }
    }

#pragma unroll
    for (int t = 0; t < 8; t++)
#pragma unroll
        for (int r = 0; r < 4; r++) {
            int row = R + q * 4 + r;
            if (row < N) out[(size_t)row * D + t * 16 + c] = acc2[t][r];
        }
#undef STAGE_W
}

extern "C" void kernel_launch(void* const* d_in, const int* in_sizes, int n_in,
                              void* d_out, int out_size, void* d_ws, size_t ws_size,
                              hipStream_t stream) {
    const float* x   = (const float*)d_in[0];
    const int*   ei  = (const int*)d_in[1];
    const float* W1l = (const float*)d_in[2];
    const float* b1  = (const float*)d_in[3];
    const float* W1r = (const float*)d_in[4];
    const float* W2l = (const float*)d_in[5];
    const float* b2  = (const float*)d_in[6];
    const float* W2r = (const float*)d_in[7];
    const float* Wf  = (const float*)d_in[8];
    const float* bf  = (const float*)d_in[9];
    float* out = (float*)d_out;

    int N = in_sizes[0] / D;
    int E = in_sizes[1] / 2;

    // ws: Agh | Agl | Xh | Xl (N*D halfs each) | inv f | rs i | cnt i | cursor i |
    //     bsum[256] i | csr[E] i | pw[5*32768] ush   (~55 MB)
    // h1 (f16 hi/lo, row-interleaved) lives in d_out between the two GEMMs.
    __half* Agh = (__half*)d_ws;
    __half* Agl = Agh + (size_t)N * D;
    __half* Xh  = Agl + (size_t)N * D;
    __half* Xl  = Xh + (size_t)N * D;
    float* inv  = (float*)(Xl + (size_t)N * D);
    int*   rs     = (int*)(inv + N);
    int*   cnt    = rs + N;
    int*   cursor = cnt + N;
    int*   bsum   = cursor + N;
    int*   csr    = bsum + 256;
    unsigned short* pw = (unsigned short*)(csr + E);
    unsigned short* p1lh = pw + 0 * 32768, *p1ll = p1lh + 16384;
    unsigned short* p1rh = pw + 1 * 32768, *p1rl = p1rh + 16384;
    unsigned short* p2lh = pw + 2 * 32768, *p2ll = p2lh + 16384;
    unsigned short* p2rh = pw + 3 * 32768, *p2rl = p2rh + 16384;
    unsigned short* pfh  = pw + 4 * 32768, *pfl  = pfh + 16384;

    __half* H1 = (__half*)d_out;  // interleaved h1: row*256 halfs (hi 128 | lo 128)

    int nb = (N + SCAN_B - 1) / SCAN_B;   // 196 for N=50000 (must be <= 256)
    int n8 = N * 16;

    hipMemsetAsync(cnt, 0, (size_t)N * sizeof(int), stream);
    int pro_threads = 10240 + n8 + E;
    prologue_kernel<<<(pro_threads + 255) / 256, 256, 0, stream>>>(
        W1l, W1r, W2l, W2r, Wf, pw, x, Xh, Xl, n8, ei, E, cnt);
    scan_pass1<<<nb, SCAN_B, 0, stream>>>(cnt, rs, bsum, N);
    scan_pass3<<<nb, SCAN_B, 0, stream>>>(rs, cursor, bsum, cnt, inv, N, nb);
    fill_kernel<<<(E + 255) / 256, 256, 0, stream>>>(ei, E, cursor, csr);

    int agg_blocks = (N * 16 + 255) / 256;   // 16 lanes/node (round-6 proven)
    int gemm_blocks = (N + 63) / 64;

    // layer 1: agg from Xh; GEMM reads (agg | Xh/Xl) -> h1 interleaved in d_out
    aggregate_kernel<<<agg_blocks, 256, 0, stream>>>(Xh, 16, csr, rs, cnt, inv, Agh, Agl, N);
    mfma_gemm<1><<<gemm_blocks, 256, 0, stream>>>(
        (const uint4*)Agh, (const uint4*)Agl, (const uint4*)Xh, (const uint4*)Xl,
        (const uint4*)p1lh, (const uint4*)p1ll, (const uint4*)p1rh, (const uint4*)p1rl, b1,
        nullptr, nullptr, nullptr, nullptr, H1, N);

    // layer 2: agg from h1-hi (stride 32 uint4); GEMM + fused FC, fp32 out in place
    aggregate_kernel<<<agg_blocks, 256, 0, stream>>>(H1, 32, csr, rs, cnt, inv, Agh, Agl, N);
    mfma_gemm<2><<<gemm_blocks, 256, 0, stream>>>(
        (const uint4*)Agh, (const uint4*)Agl,
        (const uint4*)d_out, (const uint4*)d_out + 16,
        (const uint4*)p2lh, (const uint4*)p2ll, (const uint4*)p2rh, (const uint4*)p2rl, b2,
        (const uint4*)pfh, (const uint4*)pfl, bf, out, nullptr, N);
}

// Round 13
// 250.256 us; speedup vs baseline: 1.0630x; 1.0630x over previous
//
#include <hip/hip_runtime.h>
#include <hip/hip_fp16.h>

#define D 128
#define SCAN_B 256

typedef __attribute__((ext_vector_type(8))) _Float16 f16x8;
typedef __attribute__((ext_vector_type(4))) float f32x4;

typedef __attribute__((address_space(1))) const void gas_t;
typedef __attribute__((address_space(3))) void las_t;

// ---- hierarchical exclusive scan (2 kernels: pass1 + fused pass3) ----
__global__ void scan_pass1(const int* __restrict__ cnt, int* __restrict__ rs,
                           int* __restrict__ bsum, int N) {
    __shared__ int lds[SCAN_B];
    int tid = threadIdx.x;
    int i = blockIdx.x * SCAN_B + tid;
    int v = (i < N) ? cnt[i] : 0;
    lds[tid] = v;
    __syncthreads();
    for (int o = 1; o < SCAN_B; o <<= 1) {
        int t = (tid >= o) ? lds[tid - o] : 0;
        __syncthreads();
        lds[tid] += t;
        __syncthreads();
    }
    if (i < N) rs[i] = lds[tid] - v;
    if (tid == SCAN_B - 1) bsum[blockIdx.x] = lds[tid];
}

// fused: each block redundantly scans bsum (nb <= 256) to get its own offset
__global__ void scan_pass3(int* __restrict__ rs, int* __restrict__ cursor,
                           const int* __restrict__ bsum, const int* __restrict__ cnt,
                           float* __restrict__ inv, int N, int nb) {
    __shared__ int lds[SCAN_B];
    int tid = threadIdx.x;
    int v = (tid < nb) ? bsum[tid] : 0;
    lds[tid] = v;
    __syncthreads();
    for (int o = 1; o < SCAN_B; o <<= 1) {
        int t = (tid >= o) ? lds[tid - o] : 0;
        __syncthreads();
        lds[tid] += t;
        __syncthreads();
    }
    int boff = (blockIdx.x == 0) ? 0 : lds[blockIdx.x - 1];
    int i = blockIdx.x * SCAN_B + tid;
    if (i < N) {
        int vv = rs[i] + boff;
        rs[i] = vv;
        cursor[i] = vv;
        inv[i] = 1.0f / (float)max(cnt[i], 1);
    }
}

__global__ void fill_kernel(const int* __restrict__ ei, int E,
                            int* __restrict__ cursor, int* __restrict__ csr) {
    int e = blockIdx.x * blockDim.x + threadIdx.x;
    if (e < E) {
        int src = ei[e], dst = ei[E + e];
        int pos = atomicAdd(&cursor[dst], 1);
        csr[pos] = src;
    }
}

// ---- fused prologue: weight pack | fp32->f16 hi/lo cvt | degree count ----
__global__ void prologue_kernel(const float* __restrict__ W1l, const float* __restrict__ W1r,
                                const float* __restrict__ W2l, const float* __restrict__ W2r,
                                const float* __restrict__ Wf, unsigned short* __restrict__ pw,
                                const float* __restrict__ x, __half* __restrict__ xh,
                                __half* __restrict__ xl, int n8,
                                const int* __restrict__ ei, int E, int* __restrict__ cnt) {
    int t = blockIdx.x * blockDim.x + threadIdx.x;
    if (t < 10240) {
        int idx = t;
        int w = idx >> 11;
        int r = idx & 2047;
        int ks = r >> 9;
        int tt = (r >> 6) & 7;
        int lane = r & 63;
        int q = lane >> 4, n = lane & 15;
        const float* W = (w == 0) ? W1l : (w == 1) ? W1r : (w == 2) ? W2l : (w == 3) ? W2r : Wf;
        unsigned short* dh = pw + (size_t)w * 32768;
        unsigned short* dl = dh + 16384;
        int off = ((ks * 8 + tt) * 64 + lane) * 8;
#pragma unroll
        for (int j = 0; j < 8; j++) {
            float v = W[(size_t)(ks * 32 + q * 8 + j) * D + tt * 16 + n];
            __half hb = __float2half_rn(v);
            dh[off + j] = __half_as_ushort(hb);
            dl[off + j] = __half_as_ushort(__float2half_rn(v - __half2float(hb)));
        }
    } else if (t < 10240 + n8) {
        int i = t - 10240;
        const float4* x4 = (const float4*)x;
        float4 a = x4[2 * i], b = x4[2 * i + 1];
        float v[8] = {a.x, a.y, a.z, a.w, b.x, b.y, b.z, b.w};
        uint4 oh, ol;
        __half2* ph = (__half2*)&oh;
        __half2* pl = (__half2*)&ol;
#pragma unroll
        for (int jj = 0; jj < 4; jj++) {
            __half h0 = __float2half_rn(v[2 * jj]);
            __half h1 = __float2half_rn(v[2 * jj + 1]);
            ph[jj] = __halves2half2(h0, h1);
            pl[jj] = __halves2half2(__float2half_rn(v[2 * jj] - __half2float(h0)),
                                    __float2half_rn(v[2 * jj + 1] - __half2float(h1)));
        }
        ((uint4*)xh)[i] = oh;
        ((uint4*)xl)[i] = ol;
    } else {
        int e = t - 10240 - n8;
        if (e < E) atomicAdd(&cnt[ei[E + e]], 1);
    }
}

__device__ __forceinline__ void acc8(uint4 v, float* s) {
    const __half2* h = reinterpret_cast<const __half2*>(&v);
    float2 f0 = __half22float2(h[0]);
    float2 f1 = __half22float2(h[1]);
    float2 f2 = __half22float2(h[2]);
    float2 f3 = __half22float2(h[3]);
    s[0] += f0.x; s[1] += f0.y; s[2] += f1.x; s[3] += f1.y;
    s[4] += f2.x; s[5] += f2.y; s[6] += f3.x; s[7] += f3.y;
}

// ---- gather-mean aggregate: 16 lanes/node, 8 cols/lane (round-6 proven shape) ----
__global__ void aggregate_kernel(const __half* __restrict__ xh, int sstride,
                                 const int* __restrict__ csr,
                                 const int* __restrict__ rs, const int* __restrict__ cnt,
                                 const float* __restrict__ inv,
                                 __half* __restrict__ aggh, __half* __restrict__ aggl, int N) {
    int t = blockIdx.x * blockDim.x + threadIdx.x;
    int node = t >> 4;
    int c = t & 15;
    if (node >= N) return;
    int deg = cnt[node];
    int st = rs[node];
    const uint4* x4 = (const uint4*)xh;
    float s[8] = {0.f, 0.f, 0.f, 0.f, 0.f, 0.f, 0.f, 0.f};
    int i = 0;
    for (; i + 4 <= deg; i += 4) {
        int n0 = csr[st + i + 0], n1 = csr[st + i + 1];
        int n2 = csr[st + i + 2], n3 = csr[st + i + 3];
        uint4 v0 = x4[(size_t)n0 * sstride + c];
        uint4 v1 = x4[(size_t)n1 * sstride + c];
        uint4 v2 = x4[(size_t)n2 * sstride + c];
        uint4 v3 = x4[(size_t)n3 * sstride + c];
        acc8(v0, s); acc8(v1, s); acc8(v2, s); acc8(v3, s);
    }
    for (; i < deg; i++) {
        int n0 = csr[st + i];
        uint4 v0 = x4[(size_t)n0 * sstride + c];
        acc8(v0, s);
    }
    float iv = inv[node];
    uint4 oh, ol;
    __half2* ph = (__half2*)&oh;
    __half2* pl = (__half2*)&ol;
#pragma unroll
    for (int jj = 0; jj < 4; jj++) {
        float v0 = s[2 * jj] * iv, v1 = s[2 * jj + 1] * iv;
        __half h0 = __float2half_rn(v0), h1 = __float2half_rn(v1);
        ph[jj] = __halves2half2(h0, h1);
        pl[jj] = __halves2half2(__float2half_rn(v0 - __half2float(h0)),
                                __float2half_rn(v1 - __half2float(h1)));
    }
    ((uint4*)aggh)[(size_t)node * 16 + c] = oh;
    ((uint4*)aggl)[(size_t)node * 16 + c] = ol;
}

// ---- 128-row-block MFMA GEMM: W + A both staged via global_load_lds ----
// block = 8 waves x 16 rows = 128 rows. grid = ceil(N/128). K=256 in 8 steps.
// Per step: waves 0-3 stage 16KB W (round-6 pattern), waves 4-7 stage 16KB A-tile
// (per-lane global src -> linear LDS dest). 2 x 32KB double-buffer (64KB LDS).
// Halves main-W L2 traffic; FC weights staged too (8x cut). Zero A VGPR footprint.
template <int LAYER>
__global__ __launch_bounds__(512) void mfma_gemm(
        const uint4* __restrict__ Agh, const uint4* __restrict__ Agl,  // stride 16 uint4/row
        const uint4* __restrict__ Ah1, const uint4* __restrict__ Al1,  // x (s16) or h1 (s32)
        const uint4* __restrict__ W0h, const uint4* __restrict__ W0l,
        const uint4* __restrict__ W1h, const uint4* __restrict__ W1l,
        const float* __restrict__ bias,
        const uint4* __restrict__ W2h, const uint4* __restrict__ W2l,
        const float* __restrict__ bias2,
        float* out, __half* Hout, int N) {
    __shared__ uint4 smem4[4096];   // 64 KB: 2 x (W 16KB | A 16KB); FC reuses

    const int tid = threadIdx.x;
    const int lane = tid & 63;
    const int wave = tid >> 6;      // 0..7
    const int c = lane & 15;
    const int q = lane >> 4;
    const int Rblk = blockIdx.x * 128;
    const int R = Rblk + wave * 16;
    const int GS = (LAYER == 1) ? 16 : 32;

// A-stage one 16B chunk: dest uint4 index d_i in [0,1024): hi d<512 (row=d>>2,q=d&3), lo at +512
#define STAGE_A_ONE(ks_, b_, j_)                                                           \
    do {                                                                                   \
        int d_i = wa_ * 256 + (j_) * 64 + lane;                                            \
        int rr_ = (d_i & 511) >> 2;                                                        \
        int qq_ = d_i & 3;                                                                 \
        int grow_ = min(Rblk + rr_, N - 1);                                                \
        const uint4* s_;                                                                   \
        if (wave < 6) {                                                                    \
            s_ = ((ks_) < 4) ? (Agh + (size_t)grow_ * 16 + ((ks_) & 3) * 4 + qq_)          \
                             : (Ah1 + (size_t)grow_ * GS + (((ks_) - 4) & 3) * 4 + qq_);   \
        } else {                                                                           \
            s_ = ((ks_) < 4) ? (Agl + (size_t)grow_ * 16 + ((ks_) & 3) * 4 + qq_)          \
                             : (Al1 + (size_t)grow_ * GS + (((ks_) - 4) & 3) * 4 + qq_);   \
        }                                                                                  \
        uint4* dd_ = smem4 + (b_) * 2048 + 1024 + wa_ * 256 + (j_) * 64;                   \
        __builtin_amdgcn_global_load_lds((gas_t*)(s_), (las_t*)(dd_), 16, 0, 0);           \
    } while (0)

#define STAGE(ks_, b_)                                                                     \
    do {                                                                                   \
        if (wave < 4) {                                                                    \
            const uint4* sh_ = (((ks_) < 4) ? W0h : W1h) + (size_t)((ks_) & 3) * 512;      \
            const uint4* sl_ = (((ks_) < 4) ? W0l : W1l) + (size_t)((ks_) & 3) * 512;      \
            const uint4* s_ = ((wave < 2) ? sh_ : sl_) + ((wave & 1) * 256 + lane);        \
            uint4* d_ = smem4 + (b_) * 2048 + (wave >> 1) * 512 + (wave & 1) * 256;        \
            __builtin_amdgcn_global_load_lds((gas_t*)(s_), (las_t*)(d_), 16, 0, 0);        \
            __builtin_amdgcn_global_load_lds((gas_t*)(s_ + 64), (las_t*)(d_ + 64), 16, 0, 0);\
            __builtin_amdgcn_global_load_lds((gas_t*)(s_ + 128), (las_t*)(d_ + 128), 16, 0, 0);\
            __builtin_amdgcn_global_load_lds((gas_t*)(s_ + 192), (las_t*)(d_ + 192), 16, 0, 0);\
        } else {                                                                           \
            const int wa_ = wave - 4;                                                      \
            STAGE_A_ONE(ks_, b_, 0);                                                       \
            STAGE_A_ONE(ks_, b_, 1);                                                       \
            STAGE_A_ONE(ks_, b_, 2);                                                       \
            STAGE_A_ONE(ks_, b_, 3);                                                       \
        }                                                                                  \
    } while (0)

    STAGE(0, 0);
    STAGE(1, 1);
    asm volatile("s_waitcnt vmcnt(0)" ::: "memory");
    __syncthreads();

    f32x4 acc[8];
#pragma unroll
    for (int t = 0; t < 8; t++)
#pragma unroll
        for (int r = 0; r < 4; r++) acc[t][r] = 0.0f;

    const int ai = (wave * 16 + c) * 4 + q;   // this lane's A uint4 index within A region

#pragma unroll
    for (int ks = 0; ks < 8; ks++) {
        const int b = ks & 1;
        const uint4* wb = smem4 + b * 2048;
        const uint4* ab = wb + 1024;
        f16x8 ah = __builtin_bit_cast(f16x8, ab[ai]);
        f16x8 al = __builtin_bit_cast(f16x8, ab[512 + ai]);
#pragma unroll
        for (int t = 0; t < 8; t++) {
            f16x8 bh = __builtin_bit_cast(f16x8, wb[t * 64 + lane]);
            f16x8 bl = __builtin_bit_cast(f16x8, wb[512 + t * 64 + lane]);
            acc[t] = __builtin_amdgcn_mfma_f32_16x16x32_f16(ah, bh, acc[t], 0, 0, 0);
            acc[t] = __builtin_amdgcn_mfma_f32_16x16x32_f16(al, bh, acc[t], 0, 0, 0);
            acc[t] = __builtin_amdgcn_mfma_f32_16x16x32_f16(ah, bl, acc[t], 0, 0, 0);
        }
        if (ks < 7) {
            asm volatile("s_waitcnt vmcnt(0)" ::: "memory");  // stage(ks+1) landed
            __syncthreads();
            if (ks < 6) STAGE(ks + 2, b);   // overwrite just-consumed buffer
        }
    }

    // bias + row L2-norm (whole row in this wave: 16-lane shfl reduce) + relu
#pragma unroll
    for (int t = 0; t < 8; t++) {
        float bv = bias[t * 16 + c];
#pragma unroll
        for (int r = 0; r < 4; r++) acc[t][r] += bv;
    }
#pragma unroll
    for (int r = 0; r < 4; r++) {
        float v = 0.0f;
#pragma unroll
        for (int t = 0; t < 8; t++) v += acc[t][r] * acc[t][r];
        v += __shfl_xor(v, 1, 16);
        v += __shfl_xor(v, 2, 16);
        v += __shfl_xor(v, 4, 16);
        v += __shfl_xor(v, 8, 16);
        float rn = 1.0f / fmaxf(sqrtf(v), 1e-12f);
#pragma unroll
        for (int t = 0; t < 8; t++) acc[t][r] = fmaxf(acc[t][r] * rn, 0.0f);
    }

    if (LAYER == 1) {
        // write h1 row-interleaved: per row, halfs [0..127]=hi, [128..255]=lo
#pragma unroll
        for (int t = 0; t < 8; t++)
#pragma unroll
            for (int r = 0; r < 4; r++) {
                int row = R + q * 4 + r;
                if (row < N) {
                    float v = acc[t][r];
                    __half h = __float2half_rn(v);
                    size_t base = (size_t)row * 256;
                    Hout[base + t * 16 + c] = h;
                    Hout[base + 128 + t * 16 + c] = __float2half_rn(v - __half2float(h));
                }
            }
        return;
    }

    // ---- fused FC: H staged in full 64KB LDS, then FC-W staged double-buffer ----
    __syncthreads();  // all waves done reading main W/A buffers
    unsigned short* hw = (unsigned short*)(smem4 + wave * 512);   // 8KB per wave
#pragma unroll
    for (int t = 0; t < 8; t++)
#pragma unroll
        for (int r = 0; r < 4; r++) {
            int m = q * 4 + r;
            float v = acc[t][r];
            __half h = __float2half_rn(v);
            int j4 = (t * 2 + (c >> 3)) ^ (m & 7);
            int off = m * 128 + j4 * 8 + (c & 7);
            hw[off] = __half_as_ushort(h);
            hw[2048 + off] = __half_as_ushort(__float2half_rn(v - __half2float(h)));
        }
    // wave-private RAW: compiler orders via lgkmcnt (round-12 proven)
    uint4 a2h_[4], a2l_[4];
#pragma unroll
    for (int k2 = 0; k2 < 4; k2++) {
        int r4 = (k2 * 4 + q) ^ (c & 7);
        a2h_[k2] = *(const uint4*)(hw + c * 128 + r4 * 8);
        a2l_[k2] = *(const uint4*)(hw + 2048 + c * 128 + r4 * 8);
    }
    __syncthreads();  // H fully consumed into regs; LDS free for FC-W staging

// FC-W stage step k2_ into smem4 + b_*1024 (hi [0,512), lo [512,1024)); 8 waves x 2 loads
#define STAGE_F(k2_, b_)                                                                   \
    do {                                                                                   \
        const uint4* s_ = ((wave & 1) ? W2l : W2h) + (size_t)(k2_) * 512 +                 \
                          (wave >> 1) * 128 + lane;                                        \
        uint4* d_ = smem4 + (b_) * 1024 + (wave & 1) * 512 + (wave >> 1) * 128;            \
        __builtin_amdgcn_global_load_lds((gas_t*)(s_), (las_t*)(d_), 16, 0, 0);            \
        __builtin_amdgcn_global_load_lds((gas_t*)(s_ + 64), (las_t*)(d_ + 64), 16, 0, 0);  \
    } while (0)

    STAGE_F(0, 0);
    STAGE_F(1, 1);
    asm volatile("s_waitcnt vmcnt(0)" ::: "memory");
    __syncthreads();

    f32x4 acc2[8];
#pragma unroll
    for (int t = 0; t < 8; t++) {
        float bv = bias2[t * 16 + c];
#pragma unroll
        for (int r = 0; r < 4; r++) acc2[t][r] = bv;
    }
#pragma unroll
    for (int k2 = 0; k2 < 4; k2++) {
        const int b = k2 & 1;
        const uint4* wb2 = smem4 + b * 1024;
        f16x8 ah = __builtin_bit_cast(f16x8, a2h_[k2]);
        f16x8 al = __builtin_bit_cast(f16x8, a2l_[k2]);
#pragma unroll
        for (int t = 0; t < 8; t++) {
            f16x8 bh = __builtin_bit_cast(f16x8, wb2[t * 64 + lane]);
            f16x8 bl = __builtin_bit_cast(f16x8, wb2[512 + t * 64 + lane]);
            acc2[t] = __builtin_amdgcn_mfma_f32_16x16x32_f16(ah, bh, acc2[t], 0, 0, 0);
            acc2[t] = __builtin_amdgcn_mfma_f32_16x16x32_f16(al, bh, acc2[t], 0, 0, 0);
            acc2[t] = __builtin_amdgcn_mfma_f32_16x16x32_f16(ah, bl, acc2[t], 0, 0, 0);
        }
        if (k2 < 3) {
            asm volatile("s_waitcnt vmcnt(0)" ::: "memory");
            __syncthreads();
            if (k2 < 2) STAGE_F(k2 + 2, b);   // overwrite just-consumed FC buffer
        }
    }

#pragma unroll
    for (int t = 0; t < 8; t++)
#pragma unroll
        for (int r = 0; r < 4; r++) {
            int row = R + q * 4 + r;
            if (row < N) out[(size_t)row * D + t * 16 + c] = acc2[t][r];
        }
#undef STAGE
#undef STAGE_A_ONE
#undef STAGE_F
}

extern "C" void kernel_launch(void* const* d_in, const int* in_sizes, int n_in,
                              void* d_out, int out_size, void* d_ws, size_t ws_size,
                              hipStream_t stream) {
    const float* x   = (const float*)d_in[0];
    const int*   ei  = (const int*)d_in[1];
    const float* W1l = (const float*)d_in[2];
    const float* b1  = (const float*)d_in[3];
    const float* W1r = (const float*)d_in[4];
    const float* W2l = (const float*)d_in[5];
    const float* b2  = (const float*)d_in[6];
    const float* W2r = (const float*)d_in[7];
    const float* Wf  = (const float*)d_in[8];
    const float* bf  = (const float*)d_in[9];
    float* out = (float*)d_out;

    int N = in_sizes[0] / D;
    int E = in_sizes[1] / 2;

    // ws: Agh | Agl | Xh | Xl (N*D halfs each) | inv f | rs i | cnt i | cursor i |
    //     bsum[256] i | csr[E] i | pw[5*32768] ush   (~55 MB)
    // h1 (f16 hi/lo, row-interleaved) lives in d_out between the two GEMMs.
    __half* Agh = (__half*)d_ws;
    __half* Agl = Agh + (size_t)N * D;
    __half* Xh  = Agl + (size_t)N * D;
    __half* Xl  = Xh + (size_t)N * D;
    float* inv  = (float*)(Xl + (size_t)N * D);
    int*   rs     = (int*)(inv + N);
    int*   cnt    = rs + N;
    int*   cursor = cnt + N;
    int*   bsum   = cursor + N;
    int*   csr    = bsum + 256;
    unsigned short* pw = (unsigned short*)(csr + E);
    unsigned short* p1lh = pw + 0 * 32768, *p1ll = p1lh + 16384;
    unsigned short* p1rh = pw + 1 * 32768, *p1rl = p1rh + 16384;
    unsigned short* p2lh = pw + 2 * 32768, *p2ll = p2lh + 16384;
    unsigned short* p2rh = pw + 3 * 32768, *p2rl = p2rh + 16384;
    unsigned short* pfh  = pw + 4 * 32768, *pfl  = pfh + 16384;

    __half* H1 = (__half*)d_out;  // interleaved h1: row*256 halfs (hi 128 | lo 128)

    int nb = (N + SCAN_B - 1) / SCAN_B;   // 196 for N=50000 (must be <= 256)
    int n8 = N * 16;

    hipMemsetAsync(cnt, 0, (size_t)N * sizeof(int), stream);
    int pro_threads = 10240 + n8 + E;
    prologue_kernel<<<(pro_threads + 255) / 256, 256, 0, stream>>>(
        W1l, W1r, W2l, W2r, Wf, pw, x, Xh, Xl, n8, ei, E, cnt);
    scan_pass1<<<nb, SCAN_B, 0, stream>>>(cnt, rs, bsum, N);
    scan_pass3<<<nb, SCAN_B, 0, stream>>>(rs, cursor, bsum, cnt, inv, N, nb);
    fill_kernel<<<(E + 255) / 256, 256, 0, stream>>>(ei, E, cursor, csr);

    int agg_blocks = (N * 16 + 255) / 256;   // 16 lanes/node (round-6 proven)
    int gemm_blocks = (N + 127) / 128;       // 128 rows/block, 8 waves

    // layer 1: agg from Xh; GEMM reads (agg | Xh/Xl) -> h1 interleaved in d_out
    aggregate_kernel<<<agg_blocks, 256, 0, stream>>>(Xh, 16, csr, rs, cnt, inv, Agh, Agl, N);
    mfma_gemm<1><<<gemm_blocks, 512, 0, stream>>>(
        (const uint4*)Agh, (const uint4*)Agl, (const uint4*)Xh, (const uint4*)Xl,
        (const uint4*)p1lh, (const uint4*)p1ll, (const uint4*)p1rh, (const uint4*)p1rl, b1,
        nullptr, nullptr, nullptr, nullptr, H1, N);

    // layer 2: agg from h1-hi (stride 32 uint4); GEMM + fused FC, fp32 out in place
    aggregate_kernel<<<agg_blocks, 256, 0, stream>>>(H1, 32, csr, rs, cnt, inv, Agh, Agl, N);
    mfma_gemm<2><<<gemm_blocks, 512, 0, stream>>>(
        (const uint4*)Agh, (const uint4*)Agl,
        (const uint4*)d_out, (const uint4*)d_out + 16,
        (const uint4*)p2lh, (const uint4*)p2ll, (const uint4*)p2rh, (const uint4*)p2rl, b2,
        (const uint4*)pfh, (const uint4*)pfl, bf, out, nullptr, N);
}